// Round 1
// baseline (189.944 us; speedup 1.0000x reference)
//
#include <hip/hip_runtime.h>

#define B_ 8
#define N_ 1024
#define D_ 768
#define H_ 12
#define HD_ 64

typedef __attribute__((ext_vector_type(8))) short bf16x8;
typedef __attribute__((ext_vector_type(4))) short short4_t;
typedef __attribute__((ext_vector_type(4))) float f32x4;

__device__ __forceinline__ short f2bf(float f) {
  union { float f; unsigned u; } v; v.f = f;
  unsigned u = v.u;
  unsigned r = u + 0x7fffu + ((u >> 16) & 1u);
  return (short)(r >> 16);
}
__device__ __forceinline__ float bf2f(short s) {
  union { unsigned u; float f; } v;
  v.u = ((unsigned)(unsigned short)s) << 16;
  return v.f;
}

// ---------------- conversion: X f32 -> bf16 ----------------
__global__ void cvt_x_kernel(const float* __restrict__ X, short* __restrict__ Xb) {
  int i = (blockIdx.x * 256 + threadIdx.x) * 8;
  float4 a = *(const float4*)(X + i);
  float4 b = *(const float4*)(X + i + 4);
  bf16x8 o;
  o[0] = f2bf(a.x); o[1] = f2bf(a.y); o[2] = f2bf(a.z); o[3] = f2bf(a.w);
  o[4] = f2bf(b.x); o[5] = f2bf(b.y); o[6] = f2bf(b.z); o[7] = f2bf(b.w);
  *(bf16x8*)(Xb + i) = o;
}

// ---------------- conversion: W f32 -> bf16, transposed (Wt[n][k] = W[k][n]) ----------------
__global__ void cvt_w_kernel(const float* __restrict__ Wq, const float* __restrict__ Wk,
                             const float* __restrict__ Wv, short* __restrict__ Wt3) {
  const float* W = blockIdx.z == 0 ? Wq : (blockIdx.z == 1 ? Wk : Wv);
  short* O = Wt3 + (size_t)blockIdx.z * D_ * D_;
  __shared__ float t[32][33];
  int n0 = blockIdx.x * 32, k0 = blockIdx.y * 32;
  int tx = threadIdx.x, ty = threadIdx.y;
#pragma unroll
  for (int j = 0; j < 4; j++)
    t[ty + 8 * j][tx] = W[(size_t)(k0 + ty + 8 * j) * D_ + n0 + tx];
  __syncthreads();
#pragma unroll
  for (int j = 0; j < 4; j++)
    O[(size_t)(n0 + ty + 8 * j) * D_ + k0 + tx] = f2bf(t[tx][ty + 8 * j]);
}

// ---------------- QKV projection GEMM: C = X @ W + b (bf16 out, Q pre-scaled by 0.125) ----------------
__global__ __launch_bounds__(256)
void qkv_gemm_kernel(const short* __restrict__ Xb, const short* __restrict__ Wt3,
                     const float* __restrict__ bq, const float* __restrict__ bk,
                     const float* __restrict__ bv, short* __restrict__ QKV) {
  const int z = blockIdx.z;
  const short* Wt = Wt3 + (size_t)z * D_ * D_;
  const float* bias = z == 0 ? bq : (z == 1 ? bk : bv);
  short* C = QKV + (size_t)z * (B_ * N_) * D_;
  const float alpha = (z == 0) ? 0.125f : 1.0f;

  const int m0 = blockIdx.x * 128;
  const int n0 = blockIdx.y * 128;
  const int tid = threadIdx.x;
  const int lane = tid & 63;
  const int wid = tid >> 6;
  const int wr = (wid >> 1) * 64;
  const int wc = (wid & 1) * 64;
  const int l15 = lane & 15;
  const int lg = lane >> 4;

  __shared__ short At[128][40];   // 32 cols + pad to 40 (80B rows, 2-way banks = free)
  __shared__ short Bt[128][40];

  f32x4 acc[4][4];
#pragma unroll
  for (int m = 0; m < 4; m++)
#pragma unroll
    for (int n = 0; n < 4; n++)
      acc[m][n] = (f32x4){0.f, 0.f, 0.f, 0.f};

  const int sr = tid >> 1;
  const int sc = (tid & 1) * 16;

  for (int k0 = 0; k0 < D_; k0 += 32) {
    __syncthreads();
    {
      const short* ap = Xb + (size_t)(m0 + sr) * D_ + k0 + sc;
      bf16x8 a0 = *(const bf16x8*)ap;
      bf16x8 a1 = *(const bf16x8*)(ap + 8);
      short4_t* d = (short4_t*)&At[sr][sc];
      d[0] = __builtin_shufflevector(a0, a0, 0, 1, 2, 3);
      d[1] = __builtin_shufflevector(a0, a0, 4, 5, 6, 7);
      d[2] = __builtin_shufflevector(a1, a1, 0, 1, 2, 3);
      d[3] = __builtin_shufflevector(a1, a1, 4, 5, 6, 7);
      const short* bp = Wt + (size_t)(n0 + sr) * D_ + k0 + sc;
      bf16x8 b0 = *(const bf16x8*)bp;
      bf16x8 b1 = *(const bf16x8*)(bp + 8);
      short4_t* e = (short4_t*)&Bt[sr][sc];
      e[0] = __builtin_shufflevector(b0, b0, 0, 1, 2, 3);
      e[1] = __builtin_shufflevector(b0, b0, 4, 5, 6, 7);
      e[2] = __builtin_shufflevector(b1, b1, 0, 1, 2, 3);
      e[3] = __builtin_shufflevector(b1, b1, 4, 5, 6, 7);
    }
    __syncthreads();

    bf16x8 af[4], bfr[4];
#pragma unroll
    for (int m = 0; m < 4; m++) {
      const short* p = &At[wr + m * 16 + l15][8 * lg];
      short4_t lo = *(const short4_t*)p;
      short4_t hi = *(const short4_t*)(p + 4);
      af[m] = __builtin_shufflevector(lo, hi, 0, 1, 2, 3, 4, 5, 6, 7);
    }
#pragma unroll
    for (int n = 0; n < 4; n++) {
      const short* p = &Bt[wc + n * 16 + l15][8 * lg];
      short4_t lo = *(const short4_t*)p;
      short4_t hi = *(const short4_t*)(p + 4);
      bfr[n] = __builtin_shufflevector(lo, hi, 0, 1, 2, 3, 4, 5, 6, 7);
    }
#pragma unroll
    for (int m = 0; m < 4; m++)
#pragma unroll
      for (int n = 0; n < 4; n++)
        acc[m][n] = __builtin_amdgcn_mfma_f32_16x16x32_bf16(af[m], bfr[n], acc[m][n], 0, 0, 0);
  }

#pragma unroll
  for (int n = 0; n < 4; n++) {
    const int col = n0 + wc + n * 16 + l15;
    const float bval = bias[col];
#pragma unroll
    for (int m = 0; m < 4; m++) {
#pragma unroll
      for (int r = 0; r < 4; r++) {
        const int row = m0 + wr + m * 16 + 4 * lg + r;
        C[(size_t)row * D_ + col] = f2bf((acc[m][n][r] + bval) * alpha);
      }
    }
  }
}

// ---------------- flash-style masked attention ----------------
__global__ __launch_bounds__(256)
void attn_kernel(const short* __restrict__ QKV, const float* __restrict__ adj,
                 const float* __restrict__ beta_p, float* __restrict__ out) {
  const short* Qb = QKV;
  const short* Kb = QKV + (size_t)(B_ * N_) * D_;
  const short* Vb = QKV + 2 * (size_t)(B_ * N_) * D_;

  const int qt = blockIdx.x;   // 0..15  q tile
  const int h  = blockIdx.y;   // 0..11  head
  const int b  = blockIdx.z;   // 0..7   batch
  const int tid = threadIdx.x;
  const int lane = tid & 63;
  const int w = tid >> 6;      // wave 0..3: q rows [16w,16w+16)
  const int l15 = lane & 15;
  const int lg = lane >> 4;

  const float beta = beta_p[0];
  const int q0 = qt * 64;
  const size_t seq0 = (size_t)b * N_;
  const int hc = h * HD_;

  __shared__ short Kt[64][72];       // k-tile, rows padded to 72 (144B, 16B-mult, conflict-free b128)
  __shared__ short Vt[64][68];       // v-tile, rows padded to 68 (136B)
  __shared__ short Pt[4][16][72];    // per-wave P tile

  bf16x8 qf[2];
  {
    const short* qp = Qb + (seq0 + q0 + 16 * w + l15) * (size_t)D_ + hc + 8 * lg;
    qf[0] = *(const bf16x8*)qp;
    qf[1] = *(const bf16x8*)(qp + 32);
  }

  f32x4 acc[4];
#pragma unroll
  for (int cb = 0; cb < 4; cb++) acc[cb] = (f32x4){0.f, 0.f, 0.f, 0.f};
  float mrow[4], lrow[4];
#pragma unroll
  for (int r = 0; r < 4; r++) { mrow[r] = -__builtin_inff(); lrow[r] = 0.f; }

  const float* adj_row = adj + ((size_t)b * N_ + q0 + 16 * w + 4 * lg) * (size_t)N_;

  const int srow = tid >> 3;        // 0..31
  const int scol = (tid & 7) * 8;   // 0..56

  for (int kt = 0; kt < 16; kt++) {
    const int k0 = kt * 64;
    __syncthreads();
    for (int rr = srow; rr < 64; rr += 32) {
      const short* kp = Kb + (seq0 + k0 + rr) * (size_t)D_ + hc + scol;
      bf16x8 kv = *(const bf16x8*)kp;
      *(bf16x8*)&Kt[rr][scol] = kv;
      const short* vp = Vb + (seq0 + k0 + rr) * (size_t)D_ + hc + scol;
      short4_t v0 = *(const short4_t*)vp;
      short4_t v1 = *(const short4_t*)(vp + 4);
      *(short4_t*)&Vt[rr][scol] = v0;
      *(short4_t*)&Vt[rr][scol + 4] = v1;
    }
    __syncthreads();

    // S = Q K^T (Q pre-scaled by 1/8)
    f32x4 s[4];
#pragma unroll
    for (int cb = 0; cb < 4; cb++) {
      f32x4 a = (f32x4){0.f, 0.f, 0.f, 0.f};
#pragma unroll
      for (int ks = 0; ks < 2; ks++) {
        bf16x8 kf = *(const bf16x8*)&Kt[cb * 16 + l15][8 * lg + 32 * ks];
        a = __builtin_amdgcn_mfma_f32_16x16x32_bf16(qf[ks], kf, a, 0, 0, 0);
      }
      s[cb] = a;
    }

    // mask + beta*adj, per-row tile max
    float tmax[4];
#pragma unroll
    for (int r = 0; r < 4; r++) {
      const float* ar = adj_row + (size_t)r * N_ + k0;
      float tm = -__builtin_inff();
#pragma unroll
      for (int cb = 0; cb < 4; cb++) {
        float av = ar[cb * 16 + l15];
        float sv = s[cb][r] + beta * av;
        sv = (av > 0.f) ? sv : -9.0e15f;
        s[cb][r] = sv;
        tm = fmaxf(tm, sv);
      }
      tmax[r] = tm;
    }
#pragma unroll
    for (int r = 0; r < 4; r++) {
      float t = tmax[r];
      t = fmaxf(t, __shfl_xor(t, 1));
      t = fmaxf(t, __shfl_xor(t, 2));
      t = fmaxf(t, __shfl_xor(t, 4));
      t = fmaxf(t, __shfl_xor(t, 8));
      tmax[r] = t;
    }

    // online softmax update + P write
#pragma unroll
    for (int r = 0; r < 4; r++) {
      const float mnew = fmaxf(mrow[r], tmax[r]);
      const float sc2 = __expf(mrow[r] - mnew);
      mrow[r] = mnew;
      float ps = 0.f;
#pragma unroll
      for (int cb = 0; cb < 4; cb++) {
        acc[cb][r] *= sc2;
        float pf = __expf(s[cb][r] - mnew);
        short pb = f2bf(pf);
        ps += bf2f(pb);
        Pt[w][4 * lg + r][cb * 16 + l15] = pb;
      }
      ps += __shfl_xor(ps, 1);
      ps += __shfl_xor(ps, 2);
      ps += __shfl_xor(ps, 4);
      ps += __shfl_xor(ps, 8);
      lrow[r] = lrow[r] * sc2 + ps;
    }
    __syncthreads();

    // O += P @ V
#pragma unroll
    for (int ks = 0; ks < 2; ks++) {
      bf16x8 pa = *(const bf16x8*)&Pt[w][l15][8 * lg + 32 * ks];
#pragma unroll
      for (int cb = 0; cb < 4; cb++) {
        bf16x8 vb;
#pragma unroll
        for (int i = 0; i < 8; i++)
          vb[i] = Vt[8 * lg + 32 * ks + i][cb * 16 + l15];
        acc[cb] = __builtin_amdgcn_mfma_f32_16x16x32_bf16(pa, vb, acc[cb], 0, 0, 0);
      }
    }
  }

  float inv[4];
#pragma unroll
  for (int r = 0; r < 4; r++) inv[r] = 1.f / lrow[r];
#pragma unroll
  for (int cb = 0; cb < 4; cb++) {
#pragma unroll
    for (int r = 0; r < 4; r++) {
      out[(seq0 + q0 + 16 * w + 4 * lg + r) * (size_t)D_ + hc + cb * 16 + l15] =
          acc[cb][r] * inv[r];
    }
  }
}

extern "C" void kernel_launch(void* const* d_in, const int* in_sizes, int n_in,
                              void* d_out, int out_size, void* d_ws, size_t ws_size,
                              hipStream_t stream) {
  const float* X    = (const float*)d_in[0];
  const float* adj  = (const float*)d_in[1];
  const float* Wq   = (const float*)d_in[2];
  const float* bq   = (const float*)d_in[3];
  const float* Wk   = (const float*)d_in[4];
  const float* bk   = (const float*)d_in[5];
  const float* Wv   = (const float*)d_in[6];
  const float* bv   = (const float*)d_in[7];
  const float* beta = (const float*)d_in[8];
  float* out = (float*)d_out;

  // workspace layout (bf16 shorts): Xb | Wt3 | QKV   (~54 MB total)
  short* Xb  = (short*)d_ws;
  short* Wt3 = Xb + (size_t)(B_ * N_) * D_;
  short* QKV = Wt3 + 3 * (size_t)D_ * D_;

  cvt_x_kernel<<<dim3((B_ * N_ * D_) / (256 * 8)), 256, 0, stream>>>(X, Xb);
  cvt_w_kernel<<<dim3(24, 24, 3), dim3(32, 8), 0, stream>>>(Wq, Wk, Wv, Wt3);
  qkv_gemm_kernel<<<dim3(64, 6, 3), 256, 0, stream>>>(Xb, Wt3, bq, bk, bv, QKV);
  attn_kernel<<<dim3(16, 12, 8), 256, 0, stream>>>(QKV, adj, beta, out);
}